// Round 1
// baseline (591.120 us; speedup 1.0000x reference)
//
#include <hip/hip_runtime.h>
#include <math.h>

// SoftRasterizer: B=1, V=5023, F=10000, IMG=128.
// Reference doubles faces with reversed winding; barycentrics/dist/z/color are
// winding-invariant, only `front` flips -> process each face once with
// mult = frontA + frontB for the rgb/softmax term, (1-Dp)^2 for the alpha product.
// Online softmax over depth with inv_g = 1e6 (exact: scale=exp(0)=1 when max
// unchanged), segment-parallel with a merge pass.

#define NFACE 10000
#define IMG   128
#define P_TOT (IMG*IMG)
#define NSEG  8
#define SEG_F (NFACE/NSEG)     // 1250
#define FSTR  36               // floats per face record
#define CHUNK_F 128            // faces staged in LDS per pass

// face record layout:
// 0..5  x0 y0 x1 y1 x2 y2      6..8  z0 z1 z2
// 9..13 a0 b0 a1 b1 detp       (sign-normalized so num/detp == ref w bitwise)
// 14..16 m0 m1 m2              (negative reject margins in numerator units)
// 17..19 il01 il12 il20        (1/len^2 of edges)
// 20..23 bxmin bxmax bymin bymax
// 24 mult                      25..33 tex[v][k]   34..35 pad

__device__ __forceinline__ float segd(float px, float py, float ax, float ay,
                                      float bx, float by, float il) {
    float dx = px - ax, dy = py - ay;
    float ex = bx - ax, ey = by - ay;
    float t = (dx * ex + dy * ey) * il;
    t = fminf(fmaxf(t, 0.0f), 1.0f);
    float rx = dx - t * ex, ry = dy - t * ey;
    return rx * rx + ry * ry;
}

__global__ __launch_bounds__(256) void k_pre(const float* __restrict__ v,
                                             const int* __restrict__ fc,
                                             const float* __restrict__ at,
                                             float* __restrict__ fb) {
    int f = blockIdx.x * 256 + threadIdx.x;
    if (f >= NFACE) return;
    int i0 = fc[3 * f], i1 = fc[3 * f + 1], i2 = fc[3 * f + 2];
    float x0 = -v[3 * i0], y0 = v[3 * i0 + 1], z0 = v[3 * i0 + 2];
    float x1 = -v[3 * i1], y1 = v[3 * i1 + 1], z1 = v[3 * i1 + 2];
    float x2 = -v[3 * i2], y2 = v[3 * i2 + 1], z2 = v[3 * i2 + 2];

    float det = (y1 - y2) * (x0 - x2) + (x2 - x1) * (y0 - y2);
    if (fabsf(det) < 1e-10f) det = (det < 0.0f) ? -1e-10f : 1e-10f;
    float a0 = y1 - y2, b0 = x2 - x1, a1 = y2 - y0, b1 = x0 - x2, detp = det;
    // negate both numerator coeffs and det when det<0: num'/detp' == num/det bitwise
    if (det < 0.0f) { detp = -det; a0 = -a0; b0 = -b0; a1 = -a1; b1 = -b1; }

    float a2 = a0 + a1, b2 = b0 + b1;   // |grad| of num2 = detp-num0-num1
    float g0 = sqrtf(a0 * a0 + b0 * b0);
    float g1 = sqrtf(a1 * a1 + b1 * b1);
    float g2 = sqrtf(a2 * a2 + b2 * b2);
    const float MARG = 3e-5f, AG = 1e-9f;   // contrib needs dist<1e-5; conservative
    float m0 = -(MARG * g0 + AG), m1 = -(MARG * g1 + AG), m2 = -(MARG * g2 + AG);

    float e01x = x1 - x0, e01y = y1 - y0;
    float e12x = x2 - x1, e12y = y2 - y1;
    float e20x = x0 - x2, e20y = y0 - y2;
    float il01 = 1.0f / fmaxf(e01x * e01x + e01y * e01y, 1e-12f);
    float il12 = 1.0f / fmaxf(e12x * e12x + e12y * e12y, 1e-12f);
    float il20 = 1.0f / fmaxf(e20x * e20x + e20y * e20y, 1e-12f);

    const float BM = 2e-5f;
    float bxmin = fminf(fminf(x0, x1), x2) - BM, bxmax = fmaxf(fmaxf(x0, x1), x2) + BM;
    float bymin = fminf(fminf(y0, y1), y2) - BM, bymax = fmaxf(fmaxf(y0, y1), y2) + BM;

    // front for original winding and reversed (v2,v1,v0) winding
    int mult = (((y2 - y0) * (x1 - x0)) < ((y1 - y0) * (x2 - x0)))
             + (((y0 - y2) * (x1 - x2)) < ((y1 - y2) * (x0 - x2)));

    float* F = fb + (size_t)f * FSTR;
    F[0] = x0; F[1] = y0; F[2] = x1; F[3] = y1; F[4] = x2; F[5] = y2;
    F[6] = z0; F[7] = z1; F[8] = z2;
    F[9] = a0; F[10] = b0; F[11] = a1; F[12] = b1; F[13] = detp;
    F[14] = m0; F[15] = m1; F[16] = m2;
    F[17] = il01; F[18] = il12; F[19] = il20;
    F[20] = bxmin; F[21] = bxmax; F[22] = bymin; F[23] = bymax;
    F[24] = (float)mult;
#pragma unroll
    for (int k = 0; k < 9; k++) F[25 + k] = at[(size_t)f * 9 + k];
    F[34] = 0.0f; F[35] = 0.0f;
}

__global__ __launch_bounds__(256) void k_main(const float* __restrict__ fb,
                                              float* __restrict__ part) {
    __shared__ float lds[CHUNK_F * FSTR];
    int tid = threadIdx.x;
    int tileX = blockIdx.x & 7, tileY = blockIdx.x >> 3;
    int col = tileX * 16 + (tid & 15);
    int row = tileY * 16 + (tid >> 4);
    int p = row * IMG + col;
    float px = (float)(2 * col + 1 - IMG) / (float)IMG;
    float py = (float)(2 * (IMG - 1 - row) + 1 - IMG) / (float)IMG;

    int seg = blockIdx.y;
    int fbeg = seg * SEG_F;
    int fend = fbeg + SEG_F;

    float m = -__builtin_inff();
    float s = 0.0f, ca = 0.0f, cb = 0.0f, cc = 0.0f, pr = 1.0f;

    for (int base = fbeg; base < fend; base += CHUNK_F) {
        int nf = min(CHUNK_F, fend - base);
        __syncthreads();
        for (int i = tid; i < nf * FSTR; i += 256)
            lds[i] = fb[(size_t)base * FSTR + i];
        __syncthreads();

        for (int j = 0; j < nf; ++j) {
            const float* F = &lds[j * FSTR];
            float bxmin = F[20], bxmax = F[21], bymin = F[22], bymax = F[23];
            bool inbox = (px >= bxmin) & (px <= bxmax) & (py >= bymin) & (py <= bymax);
            if (!__any(inbox)) continue;

            float x2 = F[4], y2 = F[5];
            float dx2 = px - x2, dy2 = py - y2;
            float a0 = F[9], b0 = F[10], a1 = F[11], b1 = F[12], detp = F[13];
            float num0 = a0 * dx2 + b0 * dy2;
            float num1 = a1 * dx2 + b1 * dy2;
            float num2 = detp - num0 - num1;
            bool maybe = inbox & (num0 >= F[14]) & (num1 >= F[15]) & (num2 >= F[16]);
            if (!__any(maybe)) continue;

            float x0 = F[0], y0 = F[1], x1 = F[2], y1 = F[3];
            float d01 = segd(px, py, x0, y0, x1, y1, F[17]);
            float d12 = segd(px, py, x1, y1, x2, y2, F[18]);
            float d20 = segd(px, py, x2, y2, x0, y0, F[19]);
            float dis = fminf(fminf(d01, d12), d20);

            float w0 = num0 / detp;       // bitwise == ref num/det
            float w1 = num1 / detp;
            float w2 = 1.0f - w0 - w1;
            bool inside = (w0 >= 0.0f) & (w1 >= 0.0f) & (w2 >= 0.0f);
            bool contrib = maybe & (inside | (dis < 1e-10f));
            if (!__any(contrib)) continue;

            // Dp = sigmoid(sgn*dis/SIGMA), stable
            float q = dis / 1e-6f;
            float xs_ = inside ? q : -q;
            float t = expf(-fabsf(xs_));
            float Dp = (xs_ >= 0.0f ? 1.0f : t) / (1.0f + t);
            Dp = contrib ? Dp : 0.0f;
            float omd = 1.0f - Dp;
            pr *= contrib ? (omd * omd) : 1.0f;   // both winding copies

            float multf = F[24];
            bool doz = contrib & (multf > 0.0f);
            if (__any(doz)) {
                float c0 = fminf(fmaxf(w0, 0.0f), 1.0f);
                float c1 = fminf(fmaxf(w1, 0.0f), 1.0f);
                float c2 = fminf(fmaxf(w2, 0.0f), 1.0f);
                float csum = fmaxf(c0 + c1 + c2, 1e-5f);
                c0 = c0 / csum; c1 = c1 / csum; c2 = c2 / csum;
                float zpi = c0 / F[6] + c1 / F[7] + c2 / F[8];
                if (fabsf(zpi) < 1e-12f) zpi = 1e-12f;
                float zp = 1.0f / zpi;
                if (doz & (zp >= 1.0f) & (zp <= 100.0f)) {
                    float zpn = (100.0f - zp) / 99.0f;
                    if (zpn > m) {
                        float scl = expf((m - zpn) * 1e6f);
                        s *= scl; ca *= scl; cb *= scl; cc *= scl;
                        m = zpn;
                    }
                    float arg = (zpn - m) * 1e6f;
                    if (arg > -110.0f) {   // else expf underflows to exactly 0
                        float e = expf(arg) * Dp * multf;
                        float col0 = c0 * F[25] + c1 * F[28] + c2 * F[31];
                        float col1 = c0 * F[26] + c1 * F[29] + c2 * F[32];
                        float col2 = c0 * F[27] + c1 * F[30] + c2 * F[33];
                        s += e; ca += e * col0; cb += e * col1; cc += e * col2;
                    }
                }
            }
        }
    }

    size_t pb = (size_t)(seg * 6) * P_TOT;
    part[pb + 0 * P_TOT + p] = m;
    part[pb + 1 * P_TOT + p] = s;
    part[pb + 2 * P_TOT + p] = ca;
    part[pb + 3 * P_TOT + p] = cb;
    part[pb + 4 * P_TOT + p] = cc;
    part[pb + 5 * P_TOT + p] = pr;
}

__global__ __launch_bounds__(256) void k_reduce(const float* __restrict__ part,
                                                float* __restrict__ out) {
    int p = blockIdx.x * 256 + threadIdx.x;
    float m = 0.001f;   // BG_EPS
    for (int sgi = 0; sgi < NSEG; sgi++)
        m = fmaxf(m, part[(size_t)(sgi * 6) * P_TOT + p]);
    float sum = expf((0.001f - m) * 1e6f);   // background term (s0=1)
    float a = 0.0f, b = 0.0f, c = 0.0f, pr = 1.0f;
    for (int sgi = 0; sgi < NSEG; sgi++) {
        const float* q = part + (size_t)(sgi * 6) * P_TOT;
        float w = expf((q[0 * P_TOT + p] - m) * 1e6f);   // exp(-inf)=0 for empty
        sum += q[1 * P_TOT + p] * w;
        a += q[2 * P_TOT + p] * w;
        b += q[3 * P_TOT + p] * w;
        c += q[4 * P_TOT + p] * w;
        pr *= q[5 * P_TOT + p];
    }
    out[0 * P_TOT + p] = a / sum;
    out[1 * P_TOT + p] = b / sum;
    out[2 * P_TOT + p] = c / sum;
    out[3 * P_TOT + p] = 1.0f - pr;
}

extern "C" void kernel_launch(void* const* d_in, const int* in_sizes, int n_in,
                              void* d_out, int out_size, void* d_ws, size_t ws_size,
                              hipStream_t stream) {
    const float* verts = (const float*)d_in[0];
    const int*   faces = (const int*)d_in[1];
    const float* attrs = (const float*)d_in[2];
    float* out = (float*)d_out;
    float* ws  = (float*)d_ws;

    float* fb   = ws;                          // NFACE*FSTR floats = 1.44 MB
    float* part = ws + (size_t)NFACE * FSTR;   // NSEG*6*P_TOT floats = 3.1 MB

    k_pre<<<(NFACE + 255) / 256, 256, 0, stream>>>(verts, faces, attrs, fb);
    k_main<<<dim3(64, NSEG), 256, 0, stream>>>(fb, part);
    k_reduce<<<P_TOT / 256, 256, 0, stream>>>(part, out);
}

// Round 2
// 373.767 us; speedup vs baseline: 1.5815x; 1.5815x over previous
//
#include <hip/hip_runtime.h>
#include <math.h>

// SoftRasterizer: B=1, V=5023, F=10000, IMG=128.
// R2: same math as R1 (passed, absmax 3.9e-3) but 40 face-segments instead of 8
// -> 2560 blocks (was 512) to fix occupancy/imbalance (VALUBusy was 30%,
// Occupancy 12%). nseg chosen at runtime from ws_size (deterministic).

#define NFACE 10000
#define IMG   128
#define P_TOT (IMG*IMG)
#define FSTR  36               // floats per face record
#define CHUNK_F 128            // faces staged in LDS per pass

__device__ __forceinline__ float segd(float px, float py, float ax, float ay,
                                      float bx, float by, float il) {
    float dx = px - ax, dy = py - ay;
    float ex = bx - ax, ey = by - ay;
    float t = (dx * ex + dy * ey) * il;
    t = fminf(fmaxf(t, 0.0f), 1.0f);
    float rx = dx - t * ex, ry = dy - t * ey;
    return rx * rx + ry * ry;
}

__global__ __launch_bounds__(256) void k_pre(const float* __restrict__ v,
                                             const int* __restrict__ fc,
                                             const float* __restrict__ at,
                                             float* __restrict__ fb) {
    int f = blockIdx.x * 256 + threadIdx.x;
    if (f >= NFACE) return;
    int i0 = fc[3 * f], i1 = fc[3 * f + 1], i2 = fc[3 * f + 2];
    float x0 = -v[3 * i0], y0 = v[3 * i0 + 1], z0 = v[3 * i0 + 2];
    float x1 = -v[3 * i1], y1 = v[3 * i1 + 1], z1 = v[3 * i1 + 2];
    float x2 = -v[3 * i2], y2 = v[3 * i2 + 1], z2 = v[3 * i2 + 2];

    float det = (y1 - y2) * (x0 - x2) + (x2 - x1) * (y0 - y2);
    if (fabsf(det) < 1e-10f) det = (det < 0.0f) ? -1e-10f : 1e-10f;
    float a0 = y1 - y2, b0 = x2 - x1, a1 = y2 - y0, b1 = x0 - x2, detp = det;
    if (det < 0.0f) { detp = -det; a0 = -a0; b0 = -b0; a1 = -a1; b1 = -b1; }

    float a2 = a0 + a1, b2 = b0 + b1;
    float g0 = sqrtf(a0 * a0 + b0 * b0);
    float g1 = sqrtf(a1 * a1 + b1 * b1);
    float g2 = sqrtf(a2 * a2 + b2 * b2);
    const float MARG = 3e-5f, AG = 1e-9f;
    float m0 = -(MARG * g0 + AG), m1 = -(MARG * g1 + AG), m2 = -(MARG * g2 + AG);

    float e01x = x1 - x0, e01y = y1 - y0;
    float e12x = x2 - x1, e12y = y2 - y1;
    float e20x = x0 - x2, e20y = y0 - y2;
    float il01 = 1.0f / fmaxf(e01x * e01x + e01y * e01y, 1e-12f);
    float il12 = 1.0f / fmaxf(e12x * e12x + e12y * e12y, 1e-12f);
    float il20 = 1.0f / fmaxf(e20x * e20x + e20y * e20y, 1e-12f);

    const float BM = 2e-5f;
    float bxmin = fminf(fminf(x0, x1), x2) - BM, bxmax = fmaxf(fmaxf(x0, x1), x2) + BM;
    float bymin = fminf(fminf(y0, y1), y2) - BM, bymax = fmaxf(fmaxf(y0, y1), y2) + BM;

    int mult = (((y2 - y0) * (x1 - x0)) < ((y1 - y0) * (x2 - x0)))
             + (((y0 - y2) * (x1 - x2)) < ((y1 - y2) * (x0 - x2)));

    float* F = fb + (size_t)f * FSTR;
    F[0] = x0; F[1] = y0; F[2] = x1; F[3] = y1; F[4] = x2; F[5] = y2;
    F[6] = z0; F[7] = z1; F[8] = z2;
    F[9] = a0; F[10] = b0; F[11] = a1; F[12] = b1; F[13] = detp;
    F[14] = m0; F[15] = m1; F[16] = m2;
    F[17] = il01; F[18] = il12; F[19] = il20;
    F[20] = bxmin; F[21] = bxmax; F[22] = bymin; F[23] = bymax;
    F[24] = (float)mult;
#pragma unroll
    for (int k = 0; k < 9; k++) F[25 + k] = at[(size_t)f * 9 + k];
    F[34] = 0.0f; F[35] = 0.0f;
}

__global__ __launch_bounds__(256) void k_main(const float* __restrict__ fb,
                                              float* __restrict__ part,
                                              int seg_f) {
    __shared__ float lds[CHUNK_F * FSTR];
    int tid = threadIdx.x;
    int tileX = blockIdx.x & 7, tileY = blockIdx.x >> 3;
    int col = tileX * 16 + (tid & 15);
    int row = tileY * 16 + (tid >> 4);
    int p = row * IMG + col;
    float px = (float)(2 * col + 1 - IMG) / (float)IMG;
    float py = (float)(2 * (IMG - 1 - row) + 1 - IMG) / (float)IMG;

    int seg = blockIdx.y;
    int fbeg = seg * seg_f;
    int fend = min(fbeg + seg_f, NFACE);

    float m = -__builtin_inff();
    float s = 0.0f, ca = 0.0f, cb = 0.0f, cc = 0.0f, pr = 1.0f;

    for (int base = fbeg; base < fend; base += CHUNK_F) {
        int nf = min(CHUNK_F, fend - base);
        __syncthreads();
        for (int i = tid; i < nf * FSTR; i += 256)
            lds[i] = fb[(size_t)base * FSTR + i];
        __syncthreads();

        for (int j = 0; j < nf; ++j) {
            const float* F = &lds[j * FSTR];
            float bxmin = F[20], bxmax = F[21], bymin = F[22], bymax = F[23];
            bool inbox = (px >= bxmin) & (px <= bxmax) & (py >= bymin) & (py <= bymax);
            if (!__any(inbox)) continue;

            float x2 = F[4], y2 = F[5];
            float dx2 = px - x2, dy2 = py - y2;
            float a0 = F[9], b0 = F[10], a1 = F[11], b1 = F[12], detp = F[13];
            float num0 = a0 * dx2 + b0 * dy2;
            float num1 = a1 * dx2 + b1 * dy2;
            float num2 = detp - num0 - num1;
            bool maybe = inbox & (num0 >= F[14]) & (num1 >= F[15]) & (num2 >= F[16]);
            if (!__any(maybe)) continue;

            float x0 = F[0], y0 = F[1], x1 = F[2], y1 = F[3];
            float d01 = segd(px, py, x0, y0, x1, y1, F[17]);
            float d12 = segd(px, py, x1, y1, x2, y2, F[18]);
            float d20 = segd(px, py, x2, y2, x0, y0, F[19]);
            float dis = fminf(fminf(d01, d12), d20);

            float w0 = num0 / detp;       // bitwise == ref num/det
            float w1 = num1 / detp;
            float w2 = 1.0f - w0 - w1;
            bool inside = (w0 >= 0.0f) & (w1 >= 0.0f) & (w2 >= 0.0f);
            bool contrib = maybe & (inside | (dis < 1e-10f));
            if (!__any(contrib)) continue;

            float q = dis / 1e-6f;
            float xs_ = inside ? q : -q;
            float t = expf(-fabsf(xs_));
            float Dp = (xs_ >= 0.0f ? 1.0f : t) / (1.0f + t);
            Dp = contrib ? Dp : 0.0f;
            float omd = 1.0f - Dp;
            pr *= contrib ? (omd * omd) : 1.0f;   // both winding copies

            float multf = F[24];
            bool doz = contrib & (multf > 0.0f);
            if (__any(doz)) {
                float c0 = fminf(fmaxf(w0, 0.0f), 1.0f);
                float c1 = fminf(fmaxf(w1, 0.0f), 1.0f);
                float c2 = fminf(fmaxf(w2, 0.0f), 1.0f);
                float csum = fmaxf(c0 + c1 + c2, 1e-5f);
                c0 = c0 / csum; c1 = c1 / csum; c2 = c2 / csum;
                float zpi = c0 / F[6] + c1 / F[7] + c2 / F[8];
                if (fabsf(zpi) < 1e-12f) zpi = 1e-12f;
                float zp = 1.0f / zpi;
                if (doz & (zp >= 1.0f) & (zp <= 100.0f)) {
                    float zpn = (100.0f - zp) / 99.0f;
                    if (zpn > m) {
                        float scl = expf((m - zpn) * 1e6f);
                        s *= scl; ca *= scl; cb *= scl; cc *= scl;
                        m = zpn;
                    }
                    float arg = (zpn - m) * 1e6f;
                    if (arg > -110.0f) {
                        float e = expf(arg) * Dp * multf;
                        float col0 = c0 * F[25] + c1 * F[28] + c2 * F[31];
                        float col1 = c0 * F[26] + c1 * F[29] + c2 * F[32];
                        float col2 = c0 * F[27] + c1 * F[30] + c2 * F[33];
                        s += e; ca += e * col0; cb += e * col1; cc += e * col2;
                    }
                }
            }
        }
    }

    size_t pb = (size_t)(seg * 6) * P_TOT;
    part[pb + 0 * P_TOT + p] = m;
    part[pb + 1 * P_TOT + p] = s;
    part[pb + 2 * P_TOT + p] = ca;
    part[pb + 3 * P_TOT + p] = cb;
    part[pb + 4 * P_TOT + p] = cc;
    part[pb + 5 * P_TOT + p] = pr;
}

__global__ __launch_bounds__(256) void k_reduce(const float* __restrict__ part,
                                                float* __restrict__ out,
                                                int nseg) {
    int p = blockIdx.x * 256 + threadIdx.x;
    float m = 0.001f;   // BG_EPS
    for (int sgi = 0; sgi < nseg; sgi++)
        m = fmaxf(m, part[(size_t)(sgi * 6) * P_TOT + p]);
    float sum = expf((0.001f - m) * 1e6f);   // background term (s0=1)
    float a = 0.0f, b = 0.0f, c = 0.0f, pr = 1.0f;
    for (int sgi = 0; sgi < nseg; sgi++) {
        const float* q = part + (size_t)(sgi * 6) * P_TOT;
        float w = expf((q[0 * P_TOT + p] - m) * 1e6f);   // exp(-inf)=0 for empty
        sum += q[1 * P_TOT + p] * w;
        a += q[2 * P_TOT + p] * w;
        b += q[3 * P_TOT + p] * w;
        c += q[4 * P_TOT + p] * w;
        pr *= q[5 * P_TOT + p];
    }
    out[0 * P_TOT + p] = a / sum;
    out[1 * P_TOT + p] = b / sum;
    out[2 * P_TOT + p] = c / sum;
    out[3 * P_TOT + p] = 1.0f - pr;
}

extern "C" void kernel_launch(void* const* d_in, const int* in_sizes, int n_in,
                              void* d_out, int out_size, void* d_ws, size_t ws_size,
                              hipStream_t stream) {
    const float* verts = (const float*)d_in[0];
    const int*   faces = (const int*)d_in[1];
    const float* attrs = (const float*)d_in[2];
    float* out = (float*)d_out;
    float* ws  = (float*)d_ws;

    float* fb   = ws;                          // NFACE*FSTR floats = 1.44 MB
    float* part = ws + (size_t)NFACE * FSTR;

    // pick segment count from available workspace (deterministic)
    size_t avail_f = ws_size / 4 - (size_t)NFACE * FSTR;
    int nseg_cap = (int)(avail_f / (6 * P_TOT));
    int nseg = 40;
    if (nseg_cap < 40) nseg = (nseg_cap >= 20) ? 20 : ((nseg_cap >= 10) ? 10 : 8);
    int seg_f = (NFACE + nseg - 1) / nseg;

    k_pre<<<(NFACE + 255) / 256, 256, 0, stream>>>(verts, faces, attrs, fb);
    k_main<<<dim3(64, nseg), 256, 0, stream>>>(fb, part, seg_f);
    k_reduce<<<P_TOT / 256, 256, 0, stream>>>(part, out, nseg);
}

// Round 3
// 370.872 us; speedup vs baseline: 1.5939x; 1.0078x over previous
//
#include <hip/hip_runtime.h>
#include <math.h>

// SoftRasterizer: B=1, V=5023, F=10000, IMG=128.
// R3: drop LDS staging (was capping residency at 8 blocks/CU and causing a
// heavy-block tail). Face records are wave-uniform -> scalar s_load broadcast
// from L2. 128-thread blocks (2 waves, 16x8 px), grid = 128 tiles x nseg.
// Hot-path arithmetic bit-identical to R2 (passed, absmax 3.9e-3).

#define NFACE 10000
#define IMG   128
#define P_TOT (IMG*IMG)
#define FSTR  36               // floats per face record

__device__ __forceinline__ float segd(float px, float py, float ax, float ay,
                                      float bx, float by, float il) {
    float dx = px - ax, dy = py - ay;
    float ex = bx - ax, ey = by - ay;
    float t = (dx * ex + dy * ey) * il;
    t = fminf(fmaxf(t, 0.0f), 1.0f);
    float rx = dx - t * ex, ry = dy - t * ey;
    return rx * rx + ry * ry;
}

__global__ __launch_bounds__(256) void k_pre(const float* __restrict__ v,
                                             const int* __restrict__ fc,
                                             const float* __restrict__ at,
                                             float* __restrict__ fb) {
    int f = blockIdx.x * 256 + threadIdx.x;
    if (f >= NFACE) return;
    int i0 = fc[3 * f], i1 = fc[3 * f + 1], i2 = fc[3 * f + 2];
    float x0 = -v[3 * i0], y0 = v[3 * i0 + 1], z0 = v[3 * i0 + 2];
    float x1 = -v[3 * i1], y1 = v[3 * i1 + 1], z1 = v[3 * i1 + 2];
    float x2 = -v[3 * i2], y2 = v[3 * i2 + 1], z2 = v[3 * i2 + 2];

    float det = (y1 - y2) * (x0 - x2) + (x2 - x1) * (y0 - y2);
    if (fabsf(det) < 1e-10f) det = (det < 0.0f) ? -1e-10f : 1e-10f;
    float a0 = y1 - y2, b0 = x2 - x1, a1 = y2 - y0, b1 = x0 - x2, detp = det;
    if (det < 0.0f) { detp = -det; a0 = -a0; b0 = -b0; a1 = -a1; b1 = -b1; }

    float a2 = a0 + a1, b2 = b0 + b1;
    float g0 = sqrtf(a0 * a0 + b0 * b0);
    float g1 = sqrtf(a1 * a1 + b1 * b1);
    float g2 = sqrtf(a2 * a2 + b2 * b2);
    const float MARG = 3e-5f, AG = 1e-9f;
    float m0 = -(MARG * g0 + AG), m1 = -(MARG * g1 + AG), m2 = -(MARG * g2 + AG);

    float e01x = x1 - x0, e01y = y1 - y0;
    float e12x = x2 - x1, e12y = y2 - y1;
    float e20x = x0 - x2, e20y = y0 - y2;
    float il01 = 1.0f / fmaxf(e01x * e01x + e01y * e01y, 1e-12f);
    float il12 = 1.0f / fmaxf(e12x * e12x + e12y * e12y, 1e-12f);
    float il20 = 1.0f / fmaxf(e20x * e20x + e20y * e20y, 1e-12f);

    const float BM = 2e-5f;
    float bxmin = fminf(fminf(x0, x1), x2) - BM, bxmax = fmaxf(fmaxf(x0, x1), x2) + BM;
    float bymin = fminf(fminf(y0, y1), y2) - BM, bymax = fmaxf(fmaxf(y0, y1), y2) + BM;

    int mult = (((y2 - y0) * (x1 - x0)) < ((y1 - y0) * (x2 - x0)))
             + (((y0 - y2) * (x1 - x2)) < ((y1 - y2) * (x0 - x2)));

    float* F = fb + (size_t)f * FSTR;
    F[0] = x0; F[1] = y0; F[2] = x1; F[3] = y1; F[4] = x2; F[5] = y2;
    F[6] = z0; F[7] = z1; F[8] = z2;
    F[9] = a0; F[10] = b0; F[11] = a1; F[12] = b1; F[13] = detp;
    F[14] = m0; F[15] = m1; F[16] = m2;
    F[17] = il01; F[18] = il12; F[19] = il20;
    F[20] = bxmin; F[21] = bxmax; F[22] = bymin; F[23] = bymax;
    F[24] = (float)mult;
#pragma unroll
    for (int k = 0; k < 9; k++) F[25 + k] = at[(size_t)f * 9 + k];
    F[34] = 0.0f; F[35] = 0.0f;
}

__global__ __launch_bounds__(128) void k_main(const float* __restrict__ fb,
                                              float* __restrict__ part,
                                              int seg_f) {
    int tid = threadIdx.x;
    // 8 x 16 tiles of 16x8 pixels; 2 waves per block, each wave = 16x4 region
    int tileX = blockIdx.x & 7, tileY = blockIdx.x >> 3;
    int col = tileX * 16 + (tid & 15);
    int row = tileY * 8 + (tid >> 4);
    int p = row * IMG + col;
    float px = (float)(2 * col + 1 - IMG) / (float)IMG;
    float py = (float)(2 * (IMG - 1 - row) + 1 - IMG) / (float)IMG;

    int seg = blockIdx.y;
    int fbeg = seg * seg_f;
    int fend = min(fbeg + seg_f, NFACE);

    float m = -__builtin_inff();
    float s = 0.0f, ca = 0.0f, cb = 0.0f, cc = 0.0f, pr = 1.0f;

    for (int j = fbeg; j < fend; ++j) {
        int fj = __builtin_amdgcn_readfirstlane(j);   // force wave-uniform -> s_load
        const float* F = fb + (size_t)fj * FSTR;

        float bxmin = F[20], bxmax = F[21], bymin = F[22], bymax = F[23];
        bool inbox = (px >= bxmin) & (px <= bxmax) & (py >= bymin) & (py <= bymax);
        if (!__any(inbox)) continue;

        float x2 = F[4], y2 = F[5];
        float dx2 = px - x2, dy2 = py - y2;
        float a0 = F[9], b0 = F[10], a1 = F[11], b1 = F[12], detp = F[13];
        float num0 = a0 * dx2 + b0 * dy2;
        float num1 = a1 * dx2 + b1 * dy2;
        float num2 = detp - num0 - num1;
        bool maybe = inbox & (num0 >= F[14]) & (num1 >= F[15]) & (num2 >= F[16]);
        if (!__any(maybe)) continue;

        float x0 = F[0], y0 = F[1], x1 = F[2], y1 = F[3];
        float d01 = segd(px, py, x0, y0, x1, y1, F[17]);
        float d12 = segd(px, py, x1, y1, x2, y2, F[18]);
        float d20 = segd(px, py, x2, y2, x0, y0, F[19]);
        float dis = fminf(fminf(d01, d12), d20);

        float w0 = num0 / detp;       // bitwise == ref num/det
        float w1 = num1 / detp;
        float w2 = 1.0f - w0 - w1;
        bool inside = (w0 >= 0.0f) & (w1 >= 0.0f) & (w2 >= 0.0f);
        bool contrib = maybe & (inside | (dis < 1e-10f));
        if (!__any(contrib)) continue;

        float q = dis / 1e-6f;
        float xs_ = inside ? q : -q;
        float t = expf(-fabsf(xs_));
        float Dp = (xs_ >= 0.0f ? 1.0f : t) / (1.0f + t);
        Dp = contrib ? Dp : 0.0f;
        float omd = 1.0f - Dp;
        pr *= contrib ? (omd * omd) : 1.0f;   // both winding copies

        float multf = F[24];
        bool doz = contrib & (multf > 0.0f);
        if (__any(doz)) {
            float c0 = fminf(fmaxf(w0, 0.0f), 1.0f);
            float c1 = fminf(fmaxf(w1, 0.0f), 1.0f);
            float c2 = fminf(fmaxf(w2, 0.0f), 1.0f);
            float csum = fmaxf(c0 + c1 + c2, 1e-5f);
            c0 = c0 / csum; c1 = c1 / csum; c2 = c2 / csum;
            float zpi = c0 / F[6] + c1 / F[7] + c2 / F[8];
            if (fabsf(zpi) < 1e-12f) zpi = 1e-12f;
            float zp = 1.0f / zpi;
            if (doz & (zp >= 1.0f) & (zp <= 100.0f)) {
                float zpn = (100.0f - zp) / 99.0f;
                if (zpn > m) {
                    float scl = expf((m - zpn) * 1e6f);
                    s *= scl; ca *= scl; cb *= scl; cc *= scl;
                    m = zpn;
                }
                float arg = (zpn - m) * 1e6f;
                if (arg > -110.0f) {
                    float e = expf(arg) * Dp * multf;
                    float col0 = c0 * F[25] + c1 * F[28] + c2 * F[31];
                    float col1 = c0 * F[26] + c1 * F[29] + c2 * F[32];
                    float col2 = c0 * F[27] + c1 * F[30] + c2 * F[33];
                    s += e; ca += e * col0; cb += e * col1; cc += e * col2;
                }
            }
        }
    }

    size_t pb = (size_t)(seg * 6) * P_TOT;
    part[pb + 0 * P_TOT + p] = m;
    part[pb + 1 * P_TOT + p] = s;
    part[pb + 2 * P_TOT + p] = ca;
    part[pb + 3 * P_TOT + p] = cb;
    part[pb + 4 * P_TOT + p] = cc;
    part[pb + 5 * P_TOT + p] = pr;
}

__global__ __launch_bounds__(256) void k_reduce(const float* __restrict__ part,
                                                float* __restrict__ out,
                                                int nseg) {
    int p = blockIdx.x * 256 + threadIdx.x;
    float m = 0.001f;   // BG_EPS
    for (int sgi = 0; sgi < nseg; sgi++)
        m = fmaxf(m, part[(size_t)(sgi * 6) * P_TOT + p]);
    float sum = expf((0.001f - m) * 1e6f);   // background term (s0=1)
    float a = 0.0f, b = 0.0f, c = 0.0f, pr = 1.0f;
    for (int sgi = 0; sgi < nseg; sgi++) {
        const float* q = part + (size_t)(sgi * 6) * P_TOT;
        float w = expf((q[0 * P_TOT + p] - m) * 1e6f);   // exp(-inf)=0 for empty
        sum += q[1 * P_TOT + p] * w;
        a += q[2 * P_TOT + p] * w;
        b += q[3 * P_TOT + p] * w;
        c += q[4 * P_TOT + p] * w;
        pr *= q[5 * P_TOT + p];
    }
    out[0 * P_TOT + p] = a / sum;
    out[1 * P_TOT + p] = b / sum;
    out[2 * P_TOT + p] = c / sum;
    out[3 * P_TOT + p] = 1.0f - pr;
}

extern "C" void kernel_launch(void* const* d_in, const int* in_sizes, int n_in,
                              void* d_out, int out_size, void* d_ws, size_t ws_size,
                              hipStream_t stream) {
    const float* verts = (const float*)d_in[0];
    const int*   faces = (const int*)d_in[1];
    const float* attrs = (const float*)d_in[2];
    float* out = (float*)d_out;
    float* ws  = (float*)d_ws;

    float* fb   = ws;                          // NFACE*FSTR floats = 1.44 MB
    float* part = ws + (size_t)NFACE * FSTR;

    // pick segment count from available workspace (deterministic)
    size_t avail_f = ws_size / 4 - (size_t)NFACE * FSTR;
    int nseg_cap = (int)(avail_f / (6 * P_TOT));
    int nseg = 40;
    if (nseg_cap < 40) nseg = (nseg_cap >= 20) ? 20 : ((nseg_cap >= 10) ? 10 : 8);
    int seg_f = (NFACE + nseg - 1) / nseg;

    k_pre<<<(NFACE + 255) / 256, 256, 0, stream>>>(verts, faces, attrs, fb);
    k_main<<<dim3(128, nseg), 128, 0, stream>>>(fb, part, seg_f);
    k_reduce<<<P_TOT / 256, 256, 0, stream>>>(part, out, nseg);
}